// Round 5
// baseline (209.333 us; speedup 1.0000x reference)
//
#include <hip/hip_runtime.h>
#include <hip/hip_bf16.h>

// CausalSelfAttention: B=2, T=2048, C=1024, H=16, HD=64
// fp32 I/O, bf16 MFMA internals.
//
// Round 5: fix gemm_proj epilogue OOB (row = t>>3, 2x float4 per thread) and
// Esc LDS stride -> 72 elems (16B-aligned b128 rows). Rest = round-3 structure.

typedef __attribute__((ext_vector_type(8))) __bf16 bf16x8;
typedef __attribute__((ext_vector_type(8))) short short8;
typedef __attribute__((ext_vector_type(4))) short short4v;
typedef __attribute__((ext_vector_type(4))) float floatx4;

__device__ __forceinline__ unsigned short f2b(float f) {   // RNE
    unsigned int x = __float_as_uint(f);
    x += 0x7fffu + ((x >> 16) & 1u);
    return (unsigned short)(x >> 16);
}
__device__ __forceinline__ unsigned short f2b_trunc(float f) {
    return (unsigned short)(__float_as_uint(f) >> 16);
}
__device__ __forceinline__ void gld16(const void* g, void* l) {
    __builtin_amdgcn_global_load_lds((const __attribute__((address_space(1))) void*)g,
                                     (__attribute__((address_space(3))) void*)l, 16, 0, 0);
}

// ---------------------------------------------------------------- fp32 -> bf16
__global__ __launch_bounds__(256) void cvt_k(
    const float* __restrict__ in, unsigned short* __restrict__ out, int n)
{
    int i = (blockIdx.x * 256 + threadIdx.x) << 3;
    if (i >= n) return;
    const float4 a = *(const float4*)(in + i);
    const float4 b = *(const float4*)(in + i + 4);
    short8 v;
    v[0] = (short)f2b(a.x); v[1] = (short)f2b(a.y);
    v[2] = (short)f2b(a.z); v[3] = (short)f2b(a.w);
    v[4] = (short)f2b(b.x); v[5] = (short)f2b(b.y);
    v[6] = (short)f2b(b.z); v[7] = (short)f2b(b.w);
    *(short8*)(out + i) = v;
}

// ---------------------------------------------------------------- transpose + cvt
__global__ __launch_bounds__(256) void transpose_cvt_k(
    const float* __restrict__ in, unsigned short* __restrict__ out,
    int R, int Cc)
{
    __shared__ unsigned short tl[64][72];
    const int t = threadIdx.x;
    const int r0 = blockIdx.y * 64, c0 = blockIdx.x * 64;
#pragma unroll
    for (int it = 0; it < 2; ++it) {
        int idx = it * 256 + t, r = idx >> 3, c8 = (idx & 7) << 3;
        const float* p = in + (size_t)(r0 + r) * Cc + c0 + c8;
        const float4 a = *(const float4*)p;
        const float4 b = *(const float4*)(p + 4);
        tl[r][c8 + 0] = f2b(a.x); tl[r][c8 + 1] = f2b(a.y);
        tl[r][c8 + 2] = f2b(a.z); tl[r][c8 + 3] = f2b(a.w);
        tl[r][c8 + 4] = f2b(b.x); tl[r][c8 + 5] = f2b(b.y);
        tl[r][c8 + 6] = f2b(b.z); tl[r][c8 + 7] = f2b(b.w);
    }
    __syncthreads();
#pragma unroll
    for (int it = 0; it < 2; ++it) {
        int idx = it * 256 + t, rr = idx >> 3, c8 = (idx & 7) << 3;
        short8 v;
#pragma unroll
        for (int i = 0; i < 8; ++i) v[i] = (short)tl[c8 + i][rr];
        *(short8*)(out + (size_t)(c0 + rr) * R + r0 + c8) = v;
    }
}

// ---------------------------------------------------------------- QKV GEMM
// 128x128 tiles, K=1024. LDS-reshuffle epilogue:
// q,k (col<2048) -> [B,H,T,HD] coalesced 16B stores; v -> vt [B,H,HD,T].
__global__ __launch_bounds__(256) void gemm_qkv(
    const unsigned short* __restrict__ A,     // xb [4096][1024]
    const unsigned short* __restrict__ BT,    // WTa [3072][1024]
    const float* __restrict__ bias,
    unsigned short* __restrict__ outqk,       // q at +0, k at +4194304
    unsigned short* __restrict__ outvt)       // [B,H,HD,T]
{
    __shared__ unsigned short Ald[128][32];
    __shared__ unsigned short Bld[128][32];
    __shared__ __align__(16) unsigned short Esc[128 * 72];   // stride 72 = 144B (16B-aligned rows)

    const int t = threadIdx.x;
    const int w = t >> 6, lane = t & 63, l15 = lane & 15, quad = lane >> 4;
    const int wr = w >> 1, wc = w & 1;
    const int m0 = blockIdx.y * 128, n0 = blockIdx.x * 128;
    const int K = 1024;

    float bia[4];
#pragma unroll
    for (int j = 0; j < 4; ++j) bia[j] = bias[n0 + wc * 64 + j * 16 + l15];

    floatx4 acc[4][4];
#pragma unroll
    for (int i = 0; i < 4; ++i)
#pragma unroll
        for (int j = 0; j < 4; ++j) acc[i][j] = (floatx4)0.f;

    const int row_s = t >> 2, kg_s = (t & 3) << 3;
    for (int k0 = 0; k0 < K; k0 += 32) {
        __syncthreads();
#pragma unroll
        for (int c = 0; c < 2; ++c) {
            int row = c * 64 + row_s;
            gld16(A  + (size_t)(m0 + row) * K + k0 + kg_s, &Ald[0][0] + (size_t)(c * 256 + w * 64) * 8);
            gld16(BT + (size_t)(n0 + row) * K + k0 + kg_s, &Bld[0][0] + (size_t)(c * 256 + w * 64) * 8);
        }
        __syncthreads();

        bf16x8 af[4], bfr[4];
#pragma unroll
        for (int i = 0; i < 4; ++i) af[i] = *(const bf16x8*)&Ald[wr * 64 + i * 16 + l15][quad * 8];
#pragma unroll
        for (int j = 0; j < 4; ++j) bfr[j] = *(const bf16x8*)&Bld[wc * 64 + j * 16 + l15][quad * 8];
#pragma unroll
        for (int i = 0; i < 4; ++i)
#pragma unroll
            for (int j = 0; j < 4; ++j)
                acc[i][j] = __builtin_amdgcn_mfma_f32_16x16x32_bf16(af[i], bfr[j], acc[i][j], 0, 0, 0);
    }

    // rows (tokens): m0 + wr*64 + i*16 + quad*4 + r ; cols: n0 + wc*64 + j*16 + l15
    const int bb = m0 >> 11, tbase = m0 & 2047;
    if (n0 < 2048) {
        // ---- q/k: chunk = one 64-col head; Esc as [128 t][72]
        for (int cf = 0; cf < 2; ++cf) {
            __syncthreads();
            if (wc == cf) {
#pragma unroll
                for (int i = 0; i < 4; ++i)
#pragma unroll
                    for (int j = 0; j < 4; ++j)
#pragma unroll
                        for (int r = 0; r < 4; ++r)
                            Esc[(wr * 64 + i * 16 + quad * 4 + r) * 72 + j * 16 + l15] =
                                f2b(acc[i][j][r] + bia[j]);
            }
            __syncthreads();
            const int fb = n0 + cf * 64;
            const int which = fb >> 10, h = (fb & 1023) >> 6;
            const int row = t >> 1, co = (t & 1) << 5;   // 128 rows x 32 cols per thread-pair
            const unsigned short* src = Esc + row * 72 + co;
            unsigned short* dst = outqk + (size_t)which * 4194304
                + (((size_t)(bb * 16 + h) * 2048 + tbase + row) * 64 + co);
#pragma unroll
            for (int u = 0; u < 4; ++u)
                *(short8*)(dst + u * 8) = *(const short8*)(src + u * 8);
        }
    } else {
        // ---- v: chunk = 64-token half; Esc as [128 d][72] (cols = token-in-half)
        const int hb = (n0 & 1023) >> 6;
        for (int hf = 0; hf < 2; ++hf) {
            __syncthreads();
            if (wr == hf) {
#pragma unroll
                for (int i = 0; i < 4; ++i)
#pragma unroll
                    for (int j = 0; j < 4; ++j) {
                        short4v pk;
#pragma unroll
                        for (int r = 0; r < 4; ++r) pk[r] = (short)f2b(acc[i][j][r] + bia[j]);
                        *(short4v*)&Esc[(wc * 64 + j * 16 + l15) * 72 + i * 16 + quad * 4] = pk;
                    }
            }
            __syncthreads();
            const int dl = t >> 1, co = (t & 1) << 5;
            const int h = hb + (dl >> 6), d = dl & 63;
            const unsigned short* src = Esc + dl * 72 + co;
            unsigned short* dst = outvt
                + (((size_t)(bb * 16 + h) * 64 + d) * 2048 + tbase + hf * 64 + co);
#pragma unroll
            for (int u = 0; u < 4; ++u)
                *(short8*)(dst + u * 8) = *(const short8*)(src + u * 8);
        }
    }
}

// ---------------------------------------------------------------- proj GEMM
// out[t][n] = y[t][:] @ WTp[n][:] + b[n], fp32 out. Tile 128(M)x64(N), K=1024.
__global__ __launch_bounds__(256) void gemm_proj(
    const unsigned short* __restrict__ A,     // y [4096][1024]
    const unsigned short* __restrict__ BT,    // WTp [1024][1024]
    const float* __restrict__ bias,
    float* __restrict__ outf)
{
    __shared__ unsigned short Ald[128][32];
    __shared__ unsigned short Bld[64][32];
    __shared__ __align__(16) float Ef[32 * 68];   // 68 floats = 272B (16B-aligned rows)

    const int t = threadIdx.x;
    const int w = t >> 6, lane = t & 63, l15 = lane & 15, quad = lane >> 4;
    const int m0 = blockIdx.y * 128, n0 = blockIdx.x * 64;
    const int K = 1024, N = 1024;

    float bia[4];
#pragma unroll
    for (int j = 0; j < 4; ++j) bia[j] = bias[n0 + j * 16 + l15];

    floatx4 acc[2][4];
#pragma unroll
    for (int i = 0; i < 2; ++i)
#pragma unroll
        for (int j = 0; j < 4; ++j) acc[i][j] = (floatx4)0.f;

    const int row_s = t >> 2, kg_s = (t & 3) << 3;
    for (int k0 = 0; k0 < K; k0 += 32) {
        __syncthreads();
#pragma unroll
        for (int c = 0; c < 2; ++c)
            gld16(A + (size_t)(m0 + c * 64 + row_s) * K + k0 + kg_s,
                  &Ald[0][0] + (size_t)(c * 256 + w * 64) * 8);
        gld16(BT + (size_t)(n0 + row_s) * K + k0 + kg_s,
              &Bld[0][0] + (size_t)(w * 64) * 8);
        __syncthreads();

        bf16x8 af[2], bfr[4];
#pragma unroll
        for (int i = 0; i < 2; ++i) af[i] = *(const bf16x8*)&Ald[w * 32 + i * 16 + l15][quad * 8];
#pragma unroll
        for (int j = 0; j < 4; ++j) bfr[j] = *(const bf16x8*)&Bld[j * 16 + l15][quad * 8];
#pragma unroll
        for (int i = 0; i < 2; ++i)
#pragma unroll
            for (int j = 0; j < 4; ++j)
                acc[i][j] = __builtin_amdgcn_mfma_f32_16x16x32_bf16(af[i], bfr[j], acc[i][j], 0, 0, 0);
    }

    // rows: m0 + w*32 + i*16 + quad*4 + r ; cols: n0 + j*16 + l15
    for (int qf = 0; qf < 4; ++qf) {
        __syncthreads();
        if (w == qf) {
#pragma unroll
            for (int i = 0; i < 2; ++i)
#pragma unroll
                for (int j = 0; j < 4; ++j)
#pragma unroll
                    for (int r = 0; r < 4; ++r)
                        Ef[(i * 16 + quad * 4 + r) * 68 + j * 16 + l15] = acc[i][j][r] + bia[j];
        }
        __syncthreads();
        const int row = t >> 3, co = (t & 7) << 3;   // 32 rows x 8 floats/thread
        const float* src = Ef + row * 68 + co;
        float* dst = outf + (size_t)(m0 + qf * 32 + row) * N + n0 + co;
#pragma unroll
        for (int u = 0; u < 2; ++u)
            *(float4*)(dst + u * 4) = *(const float4*)(src + u * 4);
    }
}

// ---------------------------------------------------------------- attention
// q,k: [B,H,T,HD]; vt: [B,H,HD,T]; y: [B,T,C]. One block = (b,h) x q-tile pair.
__global__ __launch_bounds__(256) void attn_k(
    const unsigned short* __restrict__ qg,
    const unsigned short* __restrict__ kg,
    const unsigned short* __restrict__ vt,
    unsigned short* __restrict__ y)
{
    __shared__ unsigned short Kb[2][64][64];   // XOR-swizzled
    __shared__ unsigned short Vb[2][64][64];
    __shared__ unsigned short Pld[4][16][72];

    const int t = threadIdx.x, w = t >> 6, lane = t & 63;
    const int l15 = lane & 15, quad = lane >> 4;
    const int bh = blockIdx.x >> 4, p = blockIdx.x & 15;
    const int b = bh >> 4, h = bh & 15;
    const float SC = 0.18033688011112042f;     // 0.125 * log2(e)

    bf16x8 ones;
#pragma unroll
    for (int i = 0; i < 8; ++i) ones[i] = (__bf16)1.0f;

    const int r_s = t >> 3;
    const int g_s = t & 7;

#pragma unroll 1
    for (int hv = 0; hv < 2; ++hv) {
        const int qt = hv ? (31 - p) : p;
        const int qbase = qt * 64;

        bf16x8 qa[2];
        {
            const unsigned short* qrow = qg + ((size_t)bh * 2048 + qbase + w * 16 + l15) * 64;
            qa[0] = *(const bf16x8*)(qrow + quad * 8);
            qa[1] = *(const bf16x8*)(qrow + 32 + quad * 8);
        }

        floatx4 O[4];
#pragma unroll
        for (int j = 0; j < 4; ++j) O[j] = (floatx4)0.f;
        floatx4 lacc = (floatx4)0.f;

        __syncthreads();
        {
#pragma unroll
            for (int c = 0; c < 2; ++c) {
                int r = c * 32 + r_s;
                int cg = (g_s ^ (r & 7)) << 3;
                gld16(kg + ((size_t)bh * 2048 + r) * 64 + cg,
                      &Kb[0][0][0] + (size_t)(c * 256 + w * 64) * 8);
                gld16(vt + ((size_t)bh * 64 + r) * 2048 + cg,
                      &Vb[0][0][0] + (size_t)(c * 256 + w * 64) * 8);
            }
        }

#pragma unroll 1
        for (int kt = 0; kt <= qt; ++kt) {
            __syncthreads();
            const int cur = kt & 1;
            if (kt < qt) {
                const int kbase = (kt + 1) * 64, nxt = cur ^ 1;
#pragma unroll
                for (int c = 0; c < 2; ++c) {
                    int r = c * 32 + r_s;
                    int cg = (g_s ^ (r & 7)) << 3;
                    gld16(kg + ((size_t)bh * 2048 + kbase + r) * 64 + cg,
                          &Kb[nxt][0][0] + (size_t)(c * 256 + w * 64) * 8);
                    gld16(vt + ((size_t)bh * 64 + r) * 2048 + kbase + cg,
                          &Vb[nxt][0][0] + (size_t)(c * 256 + w * 64) * 8);
                }
            }

            floatx4 sv[4];
#pragma unroll
            for (int jn = 0; jn < 4; ++jn) sv[jn] = (floatx4)0.f;
#pragma unroll
            for (int kk = 0; kk < 2; ++kk) {
#pragma unroll
                for (int jn = 0; jn < 4; ++jn) {
                    bf16x8 bfr = *(const bf16x8*)&Kb[cur][jn * 16 + l15][((kk * 4 + quad) ^ (l15 & 7)) << 3];
                    sv[jn] = __builtin_amdgcn_mfma_f32_16x16x32_bf16(qa[kk], bfr, sv[jn], 0, 0, 0);
                }
            }

            if (kt == qt) {
#pragma unroll
                for (int jn = 0; jn < 4; ++jn) {
                    int key = jn * 16 + l15;
#pragma unroll
                    for (int r = 0; r < 4; ++r) {
                        int qr = w * 16 + quad * 4 + r;
                        float s = (key > qr) ? -1e30f : sv[jn][r];
                        sv[jn][r] = exp2f(s * SC);
                    }
                }
            } else {
#pragma unroll
                for (int jn = 0; jn < 4; ++jn)
#pragma unroll
                    for (int r = 0; r < 4; ++r) sv[jn][r] = exp2f(sv[jn][r] * SC);
            }

#pragma unroll
            for (int jn = 0; jn < 4; ++jn)
#pragma unroll
                for (int r = 0; r < 4; ++r)
                    Pld[w][quad * 4 + r][jn * 16 + l15] = f2b_trunc(sv[jn][r]);
            __builtin_amdgcn_wave_barrier();
            __builtin_amdgcn_s_waitcnt(0xc07f);   // lgkmcnt(0)
            __builtin_amdgcn_wave_barrier();

#pragma unroll
            for (int kk = 0; kk < 2; ++kk) {
                bf16x8 pa = *(const bf16x8*)&Pld[w][l15][kk * 32 + quad * 8];
                lacc = __builtin_amdgcn_mfma_f32_16x16x32_bf16(pa, ones, lacc, 0, 0, 0);
#pragma unroll
                for (int jd = 0; jd < 4; ++jd) {
                    bf16x8 vb = *(const bf16x8*)&Vb[cur][jd * 16 + l15][((kk * 4 + quad) ^ (l15 & 7)) << 3];
                    O[jd] = __builtin_amdgcn_mfma_f32_16x16x32_bf16(pa, vb, O[jd], 0, 0, 0);
                }
            }
        }

#pragma unroll
        for (int r = 0; r < 4; ++r) {
            float inv = 1.f / lacc[r];
            int tt = qbase + w * 16 + quad * 4 + r;
#pragma unroll
            for (int jd = 0; jd < 4; ++jd) {
                int c = h * 64 + jd * 16 + l15;
                y[((size_t)b * 2048 + tt) * 1024 + c] = f2b(O[jd][r] * inv);
            }
        }
    }
}

// ---------------------------------------------------------------- launcher
extern "C" void kernel_launch(void* const* d_in, const int* in_sizes, int n_in,
                              void* d_out, int out_size, void* d_ws, size_t ws_size,
                              hipStream_t stream) {
    const float* x      = (const float*)d_in[0];
    const float* W_attn = (const float*)d_in[1];
    const float* b_attn = (const float*)d_in[2];
    const float* W_proj = (const float*)d_in[3];
    const float* b_proj = (const float*)d_in[4];
    float* out = (float*)d_out;

    char* ws = (char*)d_ws;
    unsigned short* qk  = (unsigned short*)(ws);                    // q,k (16 MB)
    unsigned short* vtb = (unsigned short*)(ws + 16777216);         // v^T (8 MB)
    unsigned short* y   = (unsigned short*)(ws + 25165824);         // 8 MB
    unsigned short* xb  = (unsigned short*)(ws + 33554432);         // 8 MB
    unsigned short* WTa = (unsigned short*)(ws + 41943040);         // 6 MB
    unsigned short* WTp = (unsigned short*)(ws + 48234496);         // 2 MB

    cvt_k<<<2048, 256, 0, stream>>>(x, xb, 4194304);
    transpose_cvt_k<<<dim3(48, 16), 256, 0, stream>>>(W_attn, WTa, 1024, 3072);
    transpose_cvt_k<<<dim3(16, 16), 256, 0, stream>>>(W_proj, WTp, 1024, 1024);
    gemm_qkv<<<dim3(24, 32), 256, 0, stream>>>(xb, WTa, b_attn, qk, vtb);
    attn_k<<<512, 256, 0, stream>>>(qk, qk + 4194304, vtb, y);
    gemm_proj<<<dim3(16, 32), 256, 0, stream>>>(y, WTp, b_proj, out);
}

// Round 6
// 203.725 us; speedup vs baseline: 1.0275x; 1.0275x over previous
//
#include <hip/hip_runtime.h>
#include <hip/hip_bf16.h>

// CausalSelfAttention: B=2, T=2048, C=1024, H=16, HD=64
// fp32 I/O, bf16 MFMA internals.
//
// Round 6: single-barrier double-buffered K-loops in both GEMMs (attn-style:
// prefetch into buf^1 after barrier, compute on buf; vmcnt drain covers loads
// issued one full iteration earlier). Epilogue LDS scratch overlays the staging
// buffers -> LDS stays 32KB, 4 blocks/CU. proj back to 128x128 tile (256 blocks).

typedef __attribute__((ext_vector_type(8))) __bf16 bf16x8;
typedef __attribute__((ext_vector_type(8))) short short8;
typedef __attribute__((ext_vector_type(4))) short short4v;
typedef __attribute__((ext_vector_type(4))) float floatx4;

__device__ __forceinline__ unsigned short f2b(float f) {   // RNE
    unsigned int x = __float_as_uint(f);
    x += 0x7fffu + ((x >> 16) & 1u);
    return (unsigned short)(x >> 16);
}
__device__ __forceinline__ unsigned short f2b_trunc(float f) {
    return (unsigned short)(__float_as_uint(f) >> 16);
}
__device__ __forceinline__ void gld16(const void* g, void* l) {
    __builtin_amdgcn_global_load_lds((const __attribute__((address_space(1))) void*)g,
                                     (__attribute__((address_space(3))) void*)l, 16, 0, 0);
}

// ---------------------------------------------------------------- fp32 -> bf16
__global__ __launch_bounds__(256) void cvt_k(
    const float* __restrict__ in, unsigned short* __restrict__ out, int n)
{
    int i = (blockIdx.x * 256 + threadIdx.x) << 3;
    if (i >= n) return;
    const float4 a = *(const float4*)(in + i);
    const float4 b = *(const float4*)(in + i + 4);
    short8 v;
    v[0] = (short)f2b(a.x); v[1] = (short)f2b(a.y);
    v[2] = (short)f2b(a.z); v[3] = (short)f2b(a.w);
    v[4] = (short)f2b(b.x); v[5] = (short)f2b(b.y);
    v[6] = (short)f2b(b.z); v[7] = (short)f2b(b.w);
    *(short8*)(out + i) = v;
}

// ---------------------------------------------------------------- transpose + cvt
__global__ __launch_bounds__(256) void transpose_cvt_k(
    const float* __restrict__ in, unsigned short* __restrict__ out,
    int R, int Cc)
{
    __shared__ unsigned short tl[64][72];
    const int t = threadIdx.x;
    const int r0 = blockIdx.y * 64, c0 = blockIdx.x * 64;
#pragma unroll
    for (int it = 0; it < 2; ++it) {
        int idx = it * 256 + t, r = idx >> 3, c8 = (idx & 7) << 3;
        const float* p = in + (size_t)(r0 + r) * Cc + c0 + c8;
        const float4 a = *(const float4*)p;
        const float4 b = *(const float4*)(p + 4);
        tl[r][c8 + 0] = f2b(a.x); tl[r][c8 + 1] = f2b(a.y);
        tl[r][c8 + 2] = f2b(a.z); tl[r][c8 + 3] = f2b(a.w);
        tl[r][c8 + 4] = f2b(b.x); tl[r][c8 + 5] = f2b(b.y);
        tl[r][c8 + 6] = f2b(b.z); tl[r][c8 + 7] = f2b(b.w);
    }
    __syncthreads();
#pragma unroll
    for (int it = 0; it < 2; ++it) {
        int idx = it * 256 + t, rr = idx >> 3, c8 = (idx & 7) << 3;
        short8 v;
#pragma unroll
        for (int i = 0; i < 8; ++i) v[i] = (short)tl[c8 + i][rr];
        *(short8*)(out + (size_t)(c0 + rr) * R + r0 + c8) = v;
    }
}

// ---------------------------------------------------------------- QKV GEMM
// 128x128 tiles, K=1024, double-buffered staging, 1 barrier/K-iter.
// LDS-reshuffle epilogue overlays the staging buffers.
__global__ __launch_bounds__(256) void gemm_qkv(
    const unsigned short* __restrict__ A,     // xb [4096][1024]
    const unsigned short* __restrict__ BT,    // WTa [3072][1024]
    const float* __restrict__ bias,
    unsigned short* __restrict__ outqk,       // q at +0, k at +4194304
    unsigned short* __restrict__ outvt)       // [B,H,HD,T]
{
    __shared__ __align__(16) unsigned short SM[2][2][128][32];  // [buf][A/B][row][k] = 32 KB
    unsigned short* Esc = &SM[0][0][0][0];                      // epilogue overlay [128][72]

    const int t = threadIdx.x;
    const int w = t >> 6, lane = t & 63, l15 = lane & 15, quad = lane >> 4;
    const int wr = w >> 1, wc = w & 1;
    const int m0 = blockIdx.y * 128, n0 = blockIdx.x * 128;
    const int K = 1024;

    float bia[4];
#pragma unroll
    for (int j = 0; j < 4; ++j) bia[j] = bias[n0 + wc * 64 + j * 16 + l15];

    floatx4 acc[4][4];
#pragma unroll
    for (int i = 0; i < 4; ++i)
#pragma unroll
        for (int j = 0; j < 4; ++j) acc[i][j] = (floatx4)0.f;

    const int row_s = t >> 2, kg_s = (t & 3) << 3;
    const unsigned short* gA = A  + (size_t)(m0 + row_s) * K + kg_s;
    const unsigned short* gB = BT + (size_t)(n0 + row_s) * K + kg_s;
    const int ldst = (w * 64) * 8;   // wave-uniform LDS chunk base (shorts)

    // prologue: stage k0=0 into buf 0
#pragma unroll
    for (int c = 0; c < 2; ++c) {
        gld16(gA + (size_t)c * 64 * K, &SM[0][0][0][0] + c * 2048 + ldst);
        gld16(gB + (size_t)c * 64 * K, &SM[0][1][0][0] + c * 2048 + ldst);
    }

    for (int it = 0; it < 32; ++it) {
        __syncthreads();                     // drains loads into buf[cur] (issued last iter)
        const int cur = it & 1;
        if (it < 31) {                       // prefetch next K-slice into other buffer
            const int k0 = (it + 1) * 32;
#pragma unroll
            for (int c = 0; c < 2; ++c) {
                gld16(gA + (size_t)c * 64 * K + k0, &SM[cur ^ 1][0][0][0] + c * 2048 + ldst);
                gld16(gB + (size_t)c * 64 * K + k0, &SM[cur ^ 1][1][0][0] + c * 2048 + ldst);
            }
        }
        bf16x8 af[4], bfr[4];
#pragma unroll
        for (int i = 0; i < 4; ++i) af[i] = *(const bf16x8*)&SM[cur][0][wr * 64 + i * 16 + l15][quad * 8];
#pragma unroll
        for (int j = 0; j < 4; ++j) bfr[j] = *(const bf16x8*)&SM[cur][1][wc * 64 + j * 16 + l15][quad * 8];
#pragma unroll
        for (int i = 0; i < 4; ++i)
#pragma unroll
            for (int j = 0; j < 4; ++j)
                acc[i][j] = __builtin_amdgcn_mfma_f32_16x16x32_bf16(af[i], bfr[j], acc[i][j], 0, 0, 0);
    }

    // rows (tokens): m0 + wr*64 + i*16 + quad*4 + r ; cols: n0 + wc*64 + j*16 + l15
    const int bb = m0 >> 11, tbase = m0 & 2047;
    if (n0 < 2048) {
        // ---- q/k: chunk = one 64-col head; Esc as [128 t][72]
        for (int cf = 0; cf < 2; ++cf) {
            __syncthreads();
            if (wc == cf) {
#pragma unroll
                for (int i = 0; i < 4; ++i)
#pragma unroll
                    for (int j = 0; j < 4; ++j)
#pragma unroll
                        for (int r = 0; r < 4; ++r)
                            Esc[(wr * 64 + i * 16 + quad * 4 + r) * 72 + j * 16 + l15] =
                                f2b(acc[i][j][r] + bia[j]);
            }
            __syncthreads();
            const int fb = n0 + cf * 64;
            const int which = fb >> 10, h = (fb & 1023) >> 6;
            const int row = t >> 1, co = (t & 1) << 5;
            const unsigned short* src = Esc + row * 72 + co;
            unsigned short* dst = outqk + (size_t)which * 4194304
                + (((size_t)(bb * 16 + h) * 2048 + tbase + row) * 64 + co);
#pragma unroll
            for (int u = 0; u < 4; ++u)
                *(short8*)(dst + u * 8) = *(const short8*)(src + u * 8);
        }
    } else {
        // ---- v: chunk = 64-token half; Esc as [128 d][72]
        const int hb = (n0 & 1023) >> 6;
        for (int hf = 0; hf < 2; ++hf) {
            __syncthreads();
            if (wr == hf) {
#pragma unroll
                for (int i = 0; i < 4; ++i)
#pragma unroll
                    for (int j = 0; j < 4; ++j) {
                        short4v pk;
#pragma unroll
                        for (int r = 0; r < 4; ++r) pk[r] = (short)f2b(acc[i][j][r] + bia[j]);
                        *(short4v*)&Esc[(wc * 64 + j * 16 + l15) * 72 + i * 16 + quad * 4] = pk;
                    }
            }
            __syncthreads();
            const int dl = t >> 1, co = (t & 1) << 5;
            const int h = hb + (dl >> 6), d = dl & 63;
            const unsigned short* src = Esc + dl * 72 + co;
            unsigned short* dst = outvt
                + (((size_t)(bb * 16 + h) * 64 + d) * 2048 + tbase + hf * 64 + co);
#pragma unroll
            for (int u = 0; u < 4; ++u)
                *(short8*)(dst + u * 8) = *(const short8*)(src + u * 8);
        }
    }
}

// ---------------------------------------------------------------- proj GEMM
// out[t][n] = y[t][:] @ WTp[n][:] + b[n], fp32 out. 128x128 tile, dbuf staging.
__global__ __launch_bounds__(256) void gemm_proj(
    const unsigned short* __restrict__ A,     // y [4096][1024]
    const unsigned short* __restrict__ BT,    // WTp [1024][1024]
    const float* __restrict__ bias,
    float* __restrict__ outf)
{
    __shared__ __align__(16) unsigned short SM[2][2][128][32];  // 32 KB
    float* Ef = (float*)&SM[0][0][0][0];                        // overlay [32][132] fp32

    const int t = threadIdx.x;
    const int w = t >> 6, lane = t & 63, l15 = lane & 15, quad = lane >> 4;
    const int wr = w >> 1, wc = w & 1;
    const int m0 = blockIdx.y * 128, n0 = blockIdx.x * 128;
    const int K = 1024, N = 1024;

    float bia[4];
#pragma unroll
    for (int j = 0; j < 4; ++j) bia[j] = bias[n0 + wc * 64 + j * 16 + l15];

    floatx4 acc[4][4];
#pragma unroll
    for (int i = 0; i < 4; ++i)
#pragma unroll
        for (int j = 0; j < 4; ++j) acc[i][j] = (floatx4)0.f;

    const int row_s = t >> 2, kg_s = (t & 3) << 3;
    const unsigned short* gA = A  + (size_t)(m0 + row_s) * K + kg_s;
    const unsigned short* gB = BT + (size_t)(n0 + row_s) * K + kg_s;
    const int ldst = (w * 64) * 8;

#pragma unroll
    for (int c = 0; c < 2; ++c) {
        gld16(gA + (size_t)c * 64 * K, &SM[0][0][0][0] + c * 2048 + ldst);
        gld16(gB + (size_t)c * 64 * K, &SM[0][1][0][0] + c * 2048 + ldst);
    }

    for (int it = 0; it < 32; ++it) {
        __syncthreads();
        const int cur = it & 1;
        if (it < 31) {
            const int k0 = (it + 1) * 32;
#pragma unroll
            for (int c = 0; c < 2; ++c) {
                gld16(gA + (size_t)c * 64 * K + k0, &SM[cur ^ 1][0][0][0] + c * 2048 + ldst);
                gld16(gB + (size_t)c * 64 * K + k0, &SM[cur ^ 1][1][0][0] + c * 2048 + ldst);
            }
        }
        bf16x8 af[4], bfr[4];
#pragma unroll
        for (int i = 0; i < 4; ++i) af[i] = *(const bf16x8*)&SM[cur][0][wr * 64 + i * 16 + l15][quad * 8];
#pragma unroll
        for (int j = 0; j < 4; ++j) bfr[j] = *(const bf16x8*)&SM[cur][1][wc * 64 + j * 16 + l15][quad * 8];
#pragma unroll
        for (int i = 0; i < 4; ++i)
#pragma unroll
            for (int j = 0; j < 4; ++j)
                acc[i][j] = __builtin_amdgcn_mfma_f32_16x16x32_bf16(af[i], bfr[j], acc[i][j], 0, 0, 0);
    }

    // epilogue: 4 chunks of 32 rows x 128 cols fp32 via Ef overlay (stride 132)
    // rows: wr*64 + i*16 + quad*4 + r  -> chunk qf owns rows [qf*32, qf*32+32)
    for (int qf = 0; qf < 4; ++qf) {
        __syncthreads();
        if (wr == (qf >> 1)) {
            const int ib = (qf & 1) * 2;
#pragma unroll
            for (int ii = 0; ii < 2; ++ii)
#pragma unroll
                for (int j = 0; j < 4; ++j)
#pragma unroll
                    for (int r = 0; r < 4; ++r)
                        Ef[(ii * 16 + quad * 4 + r) * 132 + wc * 64 + j * 16 + l15] =
                            acc[ib + ii][j][r] + bia[j];
        }
        __syncthreads();
        const int row = t >> 3, co = (t & 7) << 4;   // 32 rows x 16 floats/thread
        const float* src = Ef + row * 132 + co;
        float* dst = outf + (size_t)(m0 + qf * 32 + row) * N + n0 + co;
#pragma unroll
        for (int u = 0; u < 4; ++u)
            *(float4*)(dst + u * 4) = *(const float4*)(src + u * 4);
    }
}

// ---------------------------------------------------------------- attention
// q,k: [B,H,T,HD]; vt: [B,H,HD,T]; y: [B,T,C]. One block = (b,h) x q-tile pair.
__global__ __launch_bounds__(256) void attn_k(
    const unsigned short* __restrict__ qg,
    const unsigned short* __restrict__ kg,
    const unsigned short* __restrict__ vt,
    unsigned short* __restrict__ y)
{
    __shared__ unsigned short Kb[2][64][64];   // XOR-swizzled
    __shared__ unsigned short Vb[2][64][64];
    __shared__ unsigned short Pld[4][16][72];

    const int t = threadIdx.x, w = t >> 6, lane = t & 63;
    const int l15 = lane & 15, quad = lane >> 4;
    const int bh = blockIdx.x >> 4, p = blockIdx.x & 15;
    const int b = bh >> 4, h = bh & 15;
    const float SC = 0.18033688011112042f;     // 0.125 * log2(e)

    bf16x8 ones;
#pragma unroll
    for (int i = 0; i < 8; ++i) ones[i] = (__bf16)1.0f;

    const int r_s = t >> 3;
    const int g_s = t & 7;

#pragma unroll 1
    for (int hv = 0; hv < 2; ++hv) {
        const int qt = hv ? (31 - p) : p;
        const int qbase = qt * 64;

        bf16x8 qa[2];
        {
            const unsigned short* qrow = qg + ((size_t)bh * 2048 + qbase + w * 16 + l15) * 64;
            qa[0] = *(const bf16x8*)(qrow + quad * 8);
            qa[1] = *(const bf16x8*)(qrow + 32 + quad * 8);
        }

        floatx4 O[4];
#pragma unroll
        for (int j = 0; j < 4; ++j) O[j] = (floatx4)0.f;
        floatx4 lacc = (floatx4)0.f;

        __syncthreads();
        {
#pragma unroll
            for (int c = 0; c < 2; ++c) {
                int r = c * 32 + r_s;
                int cg = (g_s ^ (r & 7)) << 3;
                gld16(kg + ((size_t)bh * 2048 + r) * 64 + cg,
                      &Kb[0][0][0] + (size_t)(c * 256 + w * 64) * 8);
                gld16(vt + ((size_t)bh * 64 + r) * 2048 + cg,
                      &Vb[0][0][0] + (size_t)(c * 256 + w * 64) * 8);
            }
        }

#pragma unroll 1
        for (int kt = 0; kt <= qt; ++kt) {
            __syncthreads();
            const int cur = kt & 1;
            if (kt < qt) {
                const int kbase = (kt + 1) * 64, nxt = cur ^ 1;
#pragma unroll
                for (int c = 0; c < 2; ++c) {
                    int r = c * 32 + r_s;
                    int cg = (g_s ^ (r & 7)) << 3;
                    gld16(kg + ((size_t)bh * 2048 + kbase + r) * 64 + cg,
                          &Kb[nxt][0][0] + (size_t)(c * 256 + w * 64) * 8);
                    gld16(vt + ((size_t)bh * 64 + r) * 2048 + kbase + cg,
                          &Vb[nxt][0][0] + (size_t)(c * 256 + w * 64) * 8);
                }
            }

            floatx4 sv[4];
#pragma unroll
            for (int jn = 0; jn < 4; ++jn) sv[jn] = (floatx4)0.f;
#pragma unroll
            for (int kk = 0; kk < 2; ++kk) {
#pragma unroll
                for (int jn = 0; jn < 4; ++jn) {
                    bf16x8 bfr = *(const bf16x8*)&Kb[cur][jn * 16 + l15][((kk * 4 + quad) ^ (l15 & 7)) << 3];
                    sv[jn] = __builtin_amdgcn_mfma_f32_16x16x32_bf16(qa[kk], bfr, sv[jn], 0, 0, 0);
                }
            }

            if (kt == qt) {
#pragma unroll
                for (int jn = 0; jn < 4; ++jn) {
                    int key = jn * 16 + l15;
#pragma unroll
                    for (int r = 0; r < 4; ++r) {
                        int qr = w * 16 + quad * 4 + r;
                        float s = (key > qr) ? -1e30f : sv[jn][r];
                        sv[jn][r] = exp2f(s * SC);
                    }
                }
            } else {
#pragma unroll
                for (int jn = 0; jn < 4; ++jn)
#pragma unroll
                    for (int r = 0; r < 4; ++r) sv[jn][r] = exp2f(sv[jn][r] * SC);
            }

#pragma unroll
            for (int jn = 0; jn < 4; ++jn)
#pragma unroll
                for (int r = 0; r < 4; ++r)
                    Pld[w][quad * 4 + r][jn * 16 + l15] = f2b_trunc(sv[jn][r]);
            __builtin_amdgcn_wave_barrier();
            __builtin_amdgcn_s_waitcnt(0xc07f);   // lgkmcnt(0)
            __builtin_amdgcn_wave_barrier();

#pragma unroll
            for (int kk = 0; kk < 2; ++kk) {
                bf16x8 pa = *(const bf16x8*)&Pld[w][l15][kk * 32 + quad * 8];
                lacc = __builtin_amdgcn_mfma_f32_16x16x32_bf16(pa, ones, lacc, 0, 0, 0);
#pragma unroll
                for (int jd = 0; jd < 4; ++jd) {
                    bf16x8 vb = *(const bf16x8*)&Vb[cur][jd * 16 + l15][((kk * 4 + quad) ^ (l15 & 7)) << 3];
                    O[jd] = __builtin_amdgcn_mfma_f32_16x16x32_bf16(pa, vb, O[jd], 0, 0, 0);
                }
            }
        }

#pragma unroll
        for (int r = 0; r < 4; ++r) {
            float inv = 1.f / lacc[r];
            int tt = qbase + w * 16 + quad * 4 + r;
#pragma unroll
            for (int jd = 0; jd < 4; ++jd) {
                int c = h * 64 + jd * 16 + l15;
                y[((size_t)b * 2048 + tt) * 1024 + c] = f2b(O[jd][r] * inv);
            }
        }
    }
}

// ---------------------------------------------------------------- launcher
extern "C" void kernel_launch(void* const* d_in, const int* in_sizes, int n_in,
                              void* d_out, int out_size, void* d_ws, size_t ws_size,
                              hipStream_t stream) {
    const float* x      = (const float*)d_in[0];
    const float* W_attn = (const float*)d_in[1];
    const float* b_attn = (const float*)d_in[2];
    const float* W_proj = (const float*)d_in[3];
    const float* b_proj = (const float*)d_in[4];
    float* out = (float*)d_out;

    char* ws = (char*)d_ws;
    unsigned short* qk  = (unsigned short*)(ws);                    // q,k (16 MB)
    unsigned short* vtb = (unsigned short*)(ws + 16777216);         // v^T (8 MB)
    unsigned short* y   = (unsigned short*)(ws + 25165824);         // 8 MB
    unsigned short* xb  = (unsigned short*)(ws + 33554432);         // 8 MB
    unsigned short* WTa = (unsigned short*)(ws + 41943040);         // 6 MB
    unsigned short* WTp = (unsigned short*)(ws + 48234496);         // 2 MB

    cvt_k<<<2048, 256, 0, stream>>>(x, xb, 4194304);
    transpose_cvt_k<<<dim3(48, 16), 256, 0, stream>>>(W_attn, WTa, 1024, 3072);
    transpose_cvt_k<<<dim3(16, 16), 256, 0, stream>>>(W_proj, WTp, 1024, 1024);
    gemm_qkv<<<dim3(24, 32), 256, 0, stream>>>(xb, WTa, b_attn, qk, vtb);
    attn_k<<<512, 256, 0, stream>>>(qk, qk + 4194304, vtb, y);
    gemm_proj<<<dim3(8, 32), 256, 0, stream>>>(y, WTp, b_proj, out);
}

// Round 7
// 201.075 us; speedup vs baseline: 1.0411x; 1.0132x over previous
//
#include <hip/hip_runtime.h>
#include <hip/hip_bf16.h>

// CausalSelfAttention: B=2, T=2048, C=1024, H=16, HD=64
// fp32 I/O, bf16 MFMA internals.
//
// Round 7: (1) XCD-aware block swizzle in attn_k -- all 16 blocks of a (b,h)
// land on one XCD (assumes round-robin id%8 dispatch) so K/V is fetched once
// per owning XCD instead of 8x (FETCH 120MB -> ~28MB). (2) q pre-scaled by
// 0.125*log2e in the QKV epilogue (kills the per-element mul in attn's
// softmax). (3) cvt + weight transposes fused into one prep_k launch.

typedef __attribute__((ext_vector_type(8))) __bf16 bf16x8;
typedef __attribute__((ext_vector_type(8))) short short8;
typedef __attribute__((ext_vector_type(4))) short short4v;
typedef __attribute__((ext_vector_type(4))) float floatx4;

__device__ __forceinline__ unsigned short f2b(float f) {   // RNE
    unsigned int x = __float_as_uint(f);
    x += 0x7fffu + ((x >> 16) & 1u);
    return (unsigned short)(x >> 16);
}
__device__ __forceinline__ unsigned short f2b_trunc(float f) {
    return (unsigned short)(__float_as_uint(f) >> 16);
}
__device__ __forceinline__ void gld16(const void* g, void* l) {
    __builtin_amdgcn_global_load_lds((const __attribute__((address_space(1))) void*)g,
                                     (__attribute__((address_space(3))) void*)l, 16, 0, 0);
}

// ---------------------------------------------------------------- prep (fused)
// blocks [0,2048): x fp32 -> xb bf16
// blocks [2048,2816): transpose W_attn [1024,3072] -> WTa [3072,1024]
// blocks [2816,3072): transpose W_proj [1024,1024] -> WTp [1024,1024]
__global__ __launch_bounds__(256) void prep_k(
    const float* __restrict__ x,  unsigned short* __restrict__ xb,
    const float* __restrict__ Wa, unsigned short* __restrict__ WTa,
    const float* __restrict__ Wp, unsigned short* __restrict__ WTp)
{
    __shared__ unsigned short tl[64][72];
    const int id = blockIdx.x, t = threadIdx.x;

    if (id < 2048) {
        int i = (id * 256 + t) << 3;
        const float4 a = *(const float4*)(x + i);
        const float4 b = *(const float4*)(x + i + 4);
        short8 v;
        v[0] = (short)f2b(a.x); v[1] = (short)f2b(a.y);
        v[2] = (short)f2b(a.z); v[3] = (short)f2b(a.w);
        v[4] = (short)f2b(b.x); v[5] = (short)f2b(b.y);
        v[6] = (short)f2b(b.z); v[7] = (short)f2b(b.w);
        *(short8*)(xb + i) = v;
        return;
    }

    const float* in;
    unsigned short* out;
    int R, Cc, bx, by;
    if (id < 2816) {
        in = Wa; out = WTa; R = 1024; Cc = 3072;
        bx = (id - 2048) % 48; by = (id - 2048) / 48;
    } else {
        in = Wp; out = WTp; R = 1024; Cc = 1024;
        bx = (id - 2816) % 16; by = (id - 2816) / 16;
    }
    const int r0 = by * 64, c0 = bx * 64;
#pragma unroll
    for (int it = 0; it < 2; ++it) {
        int idx = it * 256 + t, r = idx >> 3, c8 = (idx & 7) << 3;
        const float* p = in + (size_t)(r0 + r) * Cc + c0 + c8;
        const float4 a = *(const float4*)p;
        const float4 b = *(const float4*)(p + 4);
        tl[r][c8 + 0] = f2b(a.x); tl[r][c8 + 1] = f2b(a.y);
        tl[r][c8 + 2] = f2b(a.z); tl[r][c8 + 3] = f2b(a.w);
        tl[r][c8 + 4] = f2b(b.x); tl[r][c8 + 5] = f2b(b.y);
        tl[r][c8 + 6] = f2b(b.z); tl[r][c8 + 7] = f2b(b.w);
    }
    __syncthreads();
#pragma unroll
    for (int it = 0; it < 2; ++it) {
        int idx = it * 256 + t, rr = idx >> 3, c8 = (idx & 7) << 3;
        short8 v;
#pragma unroll
        for (int i = 0; i < 8; ++i) v[i] = (short)tl[c8 + i][rr];
        *(short8*)(out + (size_t)(c0 + rr) * R + r0 + c8) = v;
    }
}

// ---------------------------------------------------------------- QKV GEMM
// 128x128 tiles, K=1024, double-buffered staging, 1 barrier/K-iter.
// q is pre-scaled by 0.125*log2(e). Epilogue overlays staging LDS.
__global__ __launch_bounds__(256) void gemm_qkv(
    const unsigned short* __restrict__ A,     // xb [4096][1024]
    const unsigned short* __restrict__ BT,    // WTa [3072][1024]
    const float* __restrict__ bias,
    unsigned short* __restrict__ outqk,       // q at +0, k at +4194304
    unsigned short* __restrict__ outvt)       // [B,H,HD,T]
{
    __shared__ __align__(16) unsigned short SM[2][2][128][32];  // 32 KB
    unsigned short* Esc = &SM[0][0][0][0];                      // overlay [128][72]

    const int t = threadIdx.x;
    const int w = t >> 6, lane = t & 63, l15 = lane & 15, quad = lane >> 4;
    const int wr = w >> 1, wc = w & 1;
    const int m0 = blockIdx.y * 128, n0 = blockIdx.x * 128;
    const int K = 1024;

    float bia[4];
#pragma unroll
    for (int j = 0; j < 4; ++j) bia[j] = bias[n0 + wc * 64 + j * 16 + l15];

    floatx4 acc[4][4];
#pragma unroll
    for (int i = 0; i < 4; ++i)
#pragma unroll
        for (int j = 0; j < 4; ++j) acc[i][j] = (floatx4)0.f;

    const int row_s = t >> 2, kg_s = (t & 3) << 3;
    const unsigned short* gA = A  + (size_t)(m0 + row_s) * K + kg_s;
    const unsigned short* gB = BT + (size_t)(n0 + row_s) * K + kg_s;
    const int ldst = (w * 64) * 8;

#pragma unroll
    for (int c = 0; c < 2; ++c) {
        gld16(gA + (size_t)c * 64 * K, &SM[0][0][0][0] + c * 2048 + ldst);
        gld16(gB + (size_t)c * 64 * K, &SM[0][1][0][0] + c * 2048 + ldst);
    }

    for (int it = 0; it < 32; ++it) {
        __syncthreads();
        const int cur = it & 1;
        if (it < 31) {
            const int k0 = (it + 1) * 32;
#pragma unroll
            for (int c = 0; c < 2; ++c) {
                gld16(gA + (size_t)c * 64 * K + k0, &SM[cur ^ 1][0][0][0] + c * 2048 + ldst);
                gld16(gB + (size_t)c * 64 * K + k0, &SM[cur ^ 1][1][0][0] + c * 2048 + ldst);
            }
        }
        bf16x8 af[4], bfr[4];
#pragma unroll
        for (int i = 0; i < 4; ++i) af[i] = *(const bf16x8*)&SM[cur][0][wr * 64 + i * 16 + l15][quad * 8];
#pragma unroll
        for (int j = 0; j < 4; ++j) bfr[j] = *(const bf16x8*)&SM[cur][1][wc * 64 + j * 16 + l15][quad * 8];
#pragma unroll
        for (int i = 0; i < 4; ++i)
#pragma unroll
            for (int j = 0; j < 4; ++j)
                acc[i][j] = __builtin_amdgcn_mfma_f32_16x16x32_bf16(af[i], bfr[j], acc[i][j], 0, 0, 0);
    }

    // rows (tokens): m0 + wr*64 + i*16 + quad*4 + r ; cols: n0 + wc*64 + j*16 + l15
    const int bb = m0 >> 11, tbase = m0 & 2047;
    if (n0 < 2048) {
        for (int cf = 0; cf < 2; ++cf) {
            const int fb = n0 + cf * 64;
            const int which = fb >> 10, h = (fb & 1023) >> 6;
            const float scl = (which == 0) ? 0.18033688011112042f : 1.0f;  // q pre-scale
            __syncthreads();
            if (wc == cf) {
#pragma unroll
                for (int i = 0; i < 4; ++i)
#pragma unroll
                    for (int j = 0; j < 4; ++j)
#pragma unroll
                        for (int r = 0; r < 4; ++r)
                            Esc[(wr * 64 + i * 16 + quad * 4 + r) * 72 + j * 16 + l15] =
                                f2b((acc[i][j][r] + bia[j]) * scl);
            }
            __syncthreads();
            const int row = t >> 1, co = (t & 1) << 5;
            const unsigned short* src = Esc + row * 72 + co;
            unsigned short* dst = outqk + (size_t)which * 4194304
                + (((size_t)(bb * 16 + h) * 2048 + tbase + row) * 64 + co);
#pragma unroll
            for (int u = 0; u < 4; ++u)
                *(short8*)(dst + u * 8) = *(const short8*)(src + u * 8);
        }
    } else {
        const int hb = (n0 & 1023) >> 6;
        for (int hf = 0; hf < 2; ++hf) {
            __syncthreads();
            if (wr == hf) {
#pragma unroll
                for (int i = 0; i < 4; ++i)
#pragma unroll
                    for (int j = 0; j < 4; ++j) {
                        short4v pk;
#pragma unroll
                        for (int r = 0; r < 4; ++r) pk[r] = (short)f2b(acc[i][j][r] + bia[j]);
                        *(short4v*)&Esc[(wc * 64 + j * 16 + l15) * 72 + i * 16 + quad * 4] = pk;
                    }
            }
            __syncthreads();
            const int dl = t >> 1, co = (t & 1) << 5;
            const int h = hb + (dl >> 6), d = dl & 63;
            const unsigned short* src = Esc + dl * 72 + co;
            unsigned short* dst = outvt
                + (((size_t)(bb * 16 + h) * 64 + d) * 2048 + tbase + hf * 64 + co);
#pragma unroll
            for (int u = 0; u < 4; ++u)
                *(short8*)(dst + u * 8) = *(const short8*)(src + u * 8);
        }
    }
}

// ---------------------------------------------------------------- proj GEMM
// out[t][n] = y[t][:] @ WTp[n][:] + b[n], fp32 out. 128x128 tile, dbuf staging.
__global__ __launch_bounds__(256) void gemm_proj(
    const unsigned short* __restrict__ A,     // y [4096][1024]
    const unsigned short* __restrict__ BT,    // WTp [1024][1024]
    const float* __restrict__ bias,
    float* __restrict__ outf)
{
    __shared__ __align__(16) unsigned short SM[2][2][128][32];  // 32 KB
    float* Ef = (float*)&SM[0][0][0][0];                        // overlay [32][132]

    const int t = threadIdx.x;
    const int w = t >> 6, lane = t & 63, l15 = lane & 15, quad = lane >> 4;
    const int wr = w >> 1, wc = w & 1;
    const int m0 = blockIdx.y * 128, n0 = blockIdx.x * 128;
    const int K = 1024, N = 1024;

    float bia[4];
#pragma unroll
    for (int j = 0; j < 4; ++j) bia[j] = bias[n0 + wc * 64 + j * 16 + l15];

    floatx4 acc[4][4];
#pragma unroll
    for (int i = 0; i < 4; ++i)
#pragma unroll
        for (int j = 0; j < 4; ++j) acc[i][j] = (floatx4)0.f;

    const int row_s = t >> 2, kg_s = (t & 3) << 3;
    const unsigned short* gA = A  + (size_t)(m0 + row_s) * K + kg_s;
    const unsigned short* gB = BT + (size_t)(n0 + row_s) * K + kg_s;
    const int ldst = (w * 64) * 8;

#pragma unroll
    for (int c = 0; c < 2; ++c) {
        gld16(gA + (size_t)c * 64 * K, &SM[0][0][0][0] + c * 2048 + ldst);
        gld16(gB + (size_t)c * 64 * K, &SM[0][1][0][0] + c * 2048 + ldst);
    }

    for (int it = 0; it < 32; ++it) {
        __syncthreads();
        const int cur = it & 1;
        if (it < 31) {
            const int k0 = (it + 1) * 32;
#pragma unroll
            for (int c = 0; c < 2; ++c) {
                gld16(gA + (size_t)c * 64 * K + k0, &SM[cur ^ 1][0][0][0] + c * 2048 + ldst);
                gld16(gB + (size_t)c * 64 * K + k0, &SM[cur ^ 1][1][0][0] + c * 2048 + ldst);
            }
        }
        bf16x8 af[4], bfr[4];
#pragma unroll
        for (int i = 0; i < 4; ++i) af[i] = *(const bf16x8*)&SM[cur][0][wr * 64 + i * 16 + l15][quad * 8];
#pragma unroll
        for (int j = 0; j < 4; ++j) bfr[j] = *(const bf16x8*)&SM[cur][1][wc * 64 + j * 16 + l15][quad * 8];
#pragma unroll
        for (int i = 0; i < 4; ++i)
#pragma unroll
            for (int j = 0; j < 4; ++j)
                acc[i][j] = __builtin_amdgcn_mfma_f32_16x16x32_bf16(af[i], bfr[j], acc[i][j], 0, 0, 0);
    }

    for (int qf = 0; qf < 4; ++qf) {
        __syncthreads();
        if (wr == (qf >> 1)) {
            const int ib = (qf & 1) * 2;
#pragma unroll
            for (int ii = 0; ii < 2; ++ii)
#pragma unroll
                for (int j = 0; j < 4; ++j)
#pragma unroll
                    for (int r = 0; r < 4; ++r)
                        Ef[(ii * 16 + quad * 4 + r) * 132 + wc * 64 + j * 16 + l15] =
                            acc[ib + ii][j][r] + bia[j];
        }
        __syncthreads();
        const int row = t >> 3, co = (t & 7) << 4;
        const float* src = Ef + row * 132 + co;
        float* dst = outf + (size_t)(m0 + qf * 32 + row) * N + n0 + co;
#pragma unroll
        for (int u = 0; u < 4; ++u)
            *(float4*)(dst + u * 4) = *(const float4*)(src + u * 4);
    }
}

// ---------------------------------------------------------------- attention
// q (pre-scaled), k: [B,H,T,HD]; vt: [B,H,HD,T]; y: [B,T,C].
// XCD-aware swizzle: bh = (id&7)*4 + ((id>>3)&3), p = id>>5 -- all 16 blocks
// of a (b,h) share one XCD's L2 (assuming round-robin id%8 placement).
__global__ __launch_bounds__(256) void attn_k(
    const unsigned short* __restrict__ qg,
    const unsigned short* __restrict__ kg,
    const unsigned short* __restrict__ vt,
    unsigned short* __restrict__ y)
{
    __shared__ unsigned short Kb[2][64][64];   // XOR-swizzled
    __shared__ unsigned short Vb[2][64][64];
    __shared__ unsigned short Pld[4][16][72];

    const int t = threadIdx.x, w = t >> 6, lane = t & 63;
    const int l15 = lane & 15, quad = lane >> 4;
    const int id = blockIdx.x;
    const int bh = (id & 7) * 4 + ((id >> 3) & 3);
    const int p = id >> 5;
    const int b = bh >> 4, h = bh & 15;

    bf16x8 ones;
#pragma unroll
    for (int i = 0; i < 8; ++i) ones[i] = (__bf16)1.0f;

    const int r_s = t >> 3;
    const int g_s = t & 7;

#pragma unroll 1
    for (int hv = 0; hv < 2; ++hv) {
        const int qt = hv ? (31 - p) : p;
        const int qbase = qt * 64;

        bf16x8 qa[2];
        {
            const unsigned short* qrow = qg + ((size_t)bh * 2048 + qbase + w * 16 + l15) * 64;
            qa[0] = *(const bf16x8*)(qrow + quad * 8);
            qa[1] = *(const bf16x8*)(qrow + 32 + quad * 8);
        }

        floatx4 O[4];
#pragma unroll
        for (int j = 0; j < 4; ++j) O[j] = (floatx4)0.f;
        floatx4 lacc = (floatx4)0.f;

        __syncthreads();
        {
#pragma unroll
            for (int c = 0; c < 2; ++c) {
                int r = c * 32 + r_s;
                int cg = (g_s ^ (r & 7)) << 3;
                gld16(kg + ((size_t)bh * 2048 + r) * 64 + cg,
                      &Kb[0][0][0] + (size_t)(c * 256 + w * 64) * 8);
                gld16(vt + ((size_t)bh * 64 + r) * 2048 + cg,
                      &Vb[0][0][0] + (size_t)(c * 256 + w * 64) * 8);
            }
        }

#pragma unroll 1
        for (int kt = 0; kt <= qt; ++kt) {
            __syncthreads();
            const int cur = kt & 1;
            if (kt < qt) {
                const int kbase = (kt + 1) * 64, nxt = cur ^ 1;
#pragma unroll
                for (int c = 0; c < 2; ++c) {
                    int r = c * 32 + r_s;
                    int cg = (g_s ^ (r & 7)) << 3;
                    gld16(kg + ((size_t)bh * 2048 + kbase + r) * 64 + cg,
                          &Kb[nxt][0][0] + (size_t)(c * 256 + w * 64) * 8);
                    gld16(vt + ((size_t)bh * 64 + r) * 2048 + kbase + cg,
                          &Vb[nxt][0][0] + (size_t)(c * 256 + w * 64) * 8);
                }
            }

            floatx4 sv[4];
#pragma unroll
            for (int jn = 0; jn < 4; ++jn) sv[jn] = (floatx4)0.f;
#pragma unroll
            for (int kk = 0; kk < 2; ++kk) {
#pragma unroll
                for (int jn = 0; jn < 4; ++jn) {
                    bf16x8 bfr = *(const bf16x8*)&Kb[cur][jn * 16 + l15][((kk * 4 + quad) ^ (l15 & 7)) << 3];
                    sv[jn] = __builtin_amdgcn_mfma_f32_16x16x32_bf16(qa[kk], bfr, sv[jn], 0, 0, 0);
                }
            }

            // q pre-scaled: p = exp2(S); mask diag tile only
            if (kt == qt) {
#pragma unroll
                for (int jn = 0; jn < 4; ++jn) {
                    int key = jn * 16 + l15;
#pragma unroll
                    for (int r = 0; r < 4; ++r) {
                        int qr = w * 16 + quad * 4 + r;
                        sv[jn][r] = exp2f((key > qr) ? -1e30f : sv[jn][r]);
                    }
                }
            } else {
#pragma unroll
                for (int jn = 0; jn < 4; ++jn)
#pragma unroll
                    for (int r = 0; r < 4; ++r) sv[jn][r] = exp2f(sv[jn][r]);
            }

#pragma unroll
            for (int jn = 0; jn < 4; ++jn)
#pragma unroll
                for (int r = 0; r < 4; ++r)
                    Pld[w][quad * 4 + r][jn * 16 + l15] = f2b_trunc(sv[jn][r]);
            __builtin_amdgcn_wave_barrier();
            __builtin_amdgcn_s_waitcnt(0xc07f);   // lgkmcnt(0)
            __builtin_amdgcn_wave_barrier();

#pragma unroll
            for (int kk = 0; kk < 2; ++kk) {
                bf16x8 pa = *(const bf16x8*)&Pld[w][l15][kk * 32 + quad * 8];
                lacc = __builtin_amdgcn_mfma_f32_16x16x32_bf16(pa, ones, lacc, 0, 0, 0);
#pragma unroll
                for (int jd = 0; jd < 4; ++jd) {
                    bf16x8 vb = *(const bf16x8*)&Vb[cur][jd * 16 + l15][((kk * 4 + quad) ^ (l15 & 7)) << 3];
                    O[jd] = __builtin_amdgcn_mfma_f32_16x16x32_bf16(pa, vb, O[jd], 0, 0, 0);
                }
            }
        }

#pragma unroll
        for (int r = 0; r < 4; ++r) {
            float inv = 1.f / lacc[r];
            int tt = qbase + w * 16 + quad * 4 + r;
#pragma unroll
            for (int jd = 0; jd < 4; ++jd) {
                int c = h * 64 + jd * 16 + l15;
                y[((size_t)b * 2048 + tt) * 1024 + c] = f2b(O[jd][r] * inv);
            }
        }
    }
}

// ---------------------------------------------------------------- launcher
extern "C" void kernel_launch(void* const* d_in, const int* in_sizes, int n_in,
                              void* d_out, int out_size, void* d_ws, size_t ws_size,
                              hipStream_t stream) {
    const float* x      = (const float*)d_in[0];
    const float* W_attn = (const float*)d_in[1];
    const float* b_attn = (const float*)d_in[2];
    const float* W_proj = (const float*)d_in[3];
    const float* b_proj = (const float*)d_in[4];
    float* out = (float*)d_out;

    char* ws = (char*)d_ws;
    unsigned short* qk  = (unsigned short*)(ws);                    // q,k (16 MB)
    unsigned short* vtb = (unsigned short*)(ws + 16777216);         // v^T (8 MB)
    unsigned short* y   = (unsigned short*)(ws + 25165824);         // 8 MB
    unsigned short* xb  = (unsigned short*)(ws + 33554432);         // 8 MB
    unsigned short* WTa = (unsigned short*)(ws + 41943040);         // 6 MB
    unsigned short* WTp = (unsigned short*)(ws + 48234496);         // 2 MB

    prep_k<<<3072, 256, 0, stream>>>(x, xb, W_attn, WTa, W_proj, WTp);
    gemm_qkv<<<dim3(24, 32), 256, 0, stream>>>(xb, WTa, b_attn, qk, vtb);
    attn_k<<<512, 256, 0, stream>>>(qk, qk + 4194304, vtb, y);
    gemm_proj<<<dim3(8, 32), 256, 0, stream>>>(y, WTp, b_proj, out);
}